// Round 2
// baseline (537.239 us; speedup 1.0000x reference)
//
#include <hip/hip_runtime.h>

// multi_SelfAttention on MI355X (gfx950).
// Robust to inputs arriving as fp32 OR bf16: a detector kernel classifies the
// bit patterns of z, a converter materializes all inputs as bf16 in ws, and
// the final GEMM stores fp32 or bf16 per the detected flag.
// Pipeline: convert -> proj1 (z@w -> zb[8192,64] x3) -> proj2 (zb@fc+b -> Q/K/V)
//           -> flash attention -> proj3 (O@fco_w+b -> out).

typedef __bf16 bf16x8 __attribute__((ext_vector_type(8)));
typedef float floatx4 __attribute__((ext_vector_type(4)));

#define LDP 72  // padded LDS row stride (bf16): 144 B, 16B-aligned, breaks pow2 banks

// ---------------------------------------------------------------------------
// Dtype detector: interpret first 16384 u16 of z as bf16. True bf16 N(0,1)
// data has ~0% weird values; fp32 data read as bf16 pairs has ~35% (random
// low-half exponents). flag=1 -> inputs are fp32.
// ---------------------------------------------------------------------------
__global__ void detect_dtype(const unsigned short* __restrict__ z, int* __restrict__ flag) {
    __shared__ int cnt;
    if (threadIdx.x == 0) cnt = 0;
    __syncthreads();
    int local = 0;
    for (int i = threadIdx.x; i < 16384; i += 256) {
        unsigned int u = (unsigned int)z[i] << 16;
        float x = __uint_as_float(u);
        float ax = fabsf(x);
        if (!(ax <= 1024.0f) || (x != 0.0f && ax < 1e-20f)) local++;  // NaN/inf/huge/tiny
    }
    atomicAdd(&cnt, local);
    __syncthreads();
    if (threadIdx.x == 0) *flag = (cnt > 1310) ? 1 : 0;  // >8% weird -> fp32
}

// ---------------------------------------------------------------------------
// Convert all 12 inputs to bf16 in ws (fp32->bf16 or bf16 passthrough).
// ---------------------------------------------------------------------------
struct ConvArgs { const void* src[12]; int n[12]; int off[12]; };

__global__ void convert_inputs(ConvArgs a, __bf16* __restrict__ cv, const int* __restrict__ flag) {
    const int k = blockIdx.y;
    const int i = (blockIdx.x * 256 + threadIdx.x) * 8;
    if (i >= a.n[k]) return;
    __bf16* dst = cv + a.off[k] + i;
    if (*flag) {
        const float* s = (const float*)a.src[k] + i;
        float4 f0 = *(const float4*)s;
        float4 f1 = *(const float4*)(s + 4);
        bf16x8 v;
        v[0] = (__bf16)f0.x; v[1] = (__bf16)f0.y; v[2] = (__bf16)f0.z; v[3] = (__bf16)f0.w;
        v[4] = (__bf16)f1.x; v[5] = (__bf16)f1.y; v[6] = (__bf16)f1.z; v[7] = (__bf16)f1.w;
        *(bf16x8*)dst = v;
    } else {
        *(bf16x8*)dst = *(const bf16x8*)((const __bf16*)a.src[k] + i);
    }
}

// ---------------------------------------------------------------------------
// Generic tiled GEMM: C[M,N] = A[M,K] @ B[K,N] (+ bias), bf16 in, fp32 acc.
// Tile 128x64, BK=64, 256 threads (4 waves, each 32 rows x 64 cols).
// blockIdx.z selects among 3 pointer sets. Output dtype per flagp (nullptr=bf16).
// ---------------------------------------------------------------------------
__global__ __launch_bounds__(256) void gemm_bias(
    const __bf16* __restrict__ A0, const __bf16* __restrict__ A1, const __bf16* __restrict__ A2,
    const __bf16* __restrict__ B0, const __bf16* __restrict__ B1, const __bf16* __restrict__ B2,
    const __bf16* __restrict__ bias0, const __bf16* __restrict__ bias1, const __bf16* __restrict__ bias2,
    void* __restrict__ C0, void* __restrict__ C1, void* __restrict__ C2,
    int M, int N, int K, int has_bias, const int* flagp)
{
    const int zsel = blockIdx.z;
    const __bf16* A = (zsel == 0) ? A0 : (zsel == 1) ? A1 : A2;
    const __bf16* B = (zsel == 0) ? B0 : (zsel == 1) ? B1 : B2;
    const __bf16* bias = (zsel == 0) ? bias0 : (zsel == 1) ? bias1 : bias2;
    void* C = (zsel == 0) ? C0 : (zsel == 1) ? C1 : C2;
    const int out_fp32 = flagp ? *flagp : 0;

    const int m0 = blockIdx.x * 128;
    const int n0 = blockIdx.y * 64;
    const int tid = threadIdx.x;
    const int wave = tid >> 6;
    const int ln = tid & 15;
    const int quad = (tid >> 4) & 3;

    __shared__ __bf16 As[128 * LDP];   // A tile rows
    __shared__ __bf16 Bts[64 * LDP];   // B tile transposed [n][k]

    floatx4 acc[2][4] = {};

    for (int k0 = 0; k0 < K; k0 += 64) {
        __syncthreads();
        for (int i = tid; i < 1024; i += 256) {
            int r = i >> 3, c8 = (i & 7) << 3;
            *(bf16x8*)&As[r * LDP + c8] = *(const bf16x8*)&A[(m0 + r) * K + k0 + c8];
        }
        for (int i = tid; i < 512; i += 256) {
            int kk = i >> 3, nn0 = (i & 7) << 3;
            bf16x8 v = *(const bf16x8*)&B[(k0 + kk) * N + n0 + nn0];
            #pragma unroll
            for (int j = 0; j < 8; j++) Bts[(nn0 + j) * LDP + kk] = v[j];
        }
        __syncthreads();
        #pragma unroll
        for (int ks = 0; ks < 2; ks++) {
            bf16x8 a[2], b[4];
            a[0] = *(const bf16x8*)&As[(wave * 32 + ln) * LDP + ks * 32 + quad * 8];
            a[1] = *(const bf16x8*)&As[(wave * 32 + 16 + ln) * LDP + ks * 32 + quad * 8];
            #pragma unroll
            for (int nt = 0; nt < 4; nt++)
                b[nt] = *(const bf16x8*)&Bts[(nt * 16 + ln) * LDP + ks * 32 + quad * 8];
            #pragma unroll
            for (int rt = 0; rt < 2; rt++)
                #pragma unroll
                for (int nt = 0; nt < 4; nt++)
                    acc[rt][nt] = __builtin_amdgcn_mfma_f32_16x16x32_bf16(a[rt], b[nt], acc[rt][nt], 0, 0, 0);
        }
    }
    // C/D layout: col = lane&15, row = quad*4 + reg  [m89-verified]
    #pragma unroll
    for (int rt = 0; rt < 2; rt++) {
        const int row = m0 + wave * 32 + rt * 16 + quad * 4;
        #pragma unroll
        for (int nt = 0; nt < 4; nt++) {
            const int col = n0 + nt * 16 + ln;
            float bv = has_bias ? (float)bias[col] : 0.0f;
            #pragma unroll
            for (int r = 0; r < 4; r++) {
                float val = acc[rt][nt][r] + bv;
                if (out_fp32) ((float*)C)[(row + r) * N + col] = val;
                else ((__bf16*)C)[(row + r) * N + col] = (__bf16)val;
            }
        }
    }
}

// ---------------------------------------------------------------------------
// Flash attention. Q/K/V stored [B*S, H*64] bf16. One block per (b,h,q-tile128).
// 4 waves x 32 q-rows, KV tiles of 64, online softmax.
// ---------------------------------------------------------------------------
__global__ __launch_bounds__(256) void attn_kernel(
    const __bf16* __restrict__ Qg, const __bf16* __restrict__ Kg,
    const __bf16* __restrict__ Vg, __bf16* __restrict__ Og)
{
    const int bh = blockIdx.y;
    const int b = bh >> 4, h = bh & 15;
    const int q0 = blockIdx.x * 128;
    const int base = b * 2048 * 1024 + h * 64;
    const int tid = threadIdx.x;
    const int wave = tid >> 6, ln = tid & 15, quad = (tid >> 4) & 3;

    __shared__ __bf16 Qs[128 * LDP];
    __shared__ __bf16 Ks[64 * LDP];
    __shared__ __bf16 VTs[64 * LDP];   // V transposed [d][j]
    __shared__ __bf16 Ps[128 * LDP];   // per-wave P scratch

    for (int i = tid; i < 1024; i += 256) {
        int r = i >> 3, c8 = (i & 7) << 3;
        *(bf16x8*)&Qs[r * LDP + c8] = *(const bf16x8*)&Qg[base + (q0 + r) * 1024 + c8];
    }

    floatx4 o_acc[2][4] = {};
    float m_i[2][4], l_i[2][4];
    #pragma unroll
    for (int rt = 0; rt < 2; rt++)
        #pragma unroll
        for (int r = 0; r < 4; r++) { m_i[rt][r] = -1e30f; l_i[rt][r] = 0.0f; }

    const float scale = 0.125f;  // 1/sqrt(64)

    for (int t = 0; t < 32; t++) {
        const int kv0 = t * 64;
        __syncthreads();
        for (int i = tid; i < 512; i += 256) {
            int r = i >> 3, c8 = (i & 7) << 3;
            *(bf16x8*)&Ks[r * LDP + c8] = *(const bf16x8*)&Kg[base + (kv0 + r) * 1024 + c8];
            bf16x8 v = *(const bf16x8*)&Vg[base + (kv0 + r) * 1024 + c8];
            #pragma unroll
            for (int j = 0; j < 8; j++) VTs[(c8 + j) * LDP + r] = v[j];
        }
        __syncthreads();

        floatx4 s[2][4] = {};
        #pragma unroll
        for (int ks = 0; ks < 2; ks++) {
            bf16x8 a[2], bb[4];
            a[0] = *(const bf16x8*)&Qs[(wave * 32 + ln) * LDP + ks * 32 + quad * 8];
            a[1] = *(const bf16x8*)&Qs[(wave * 32 + 16 + ln) * LDP + ks * 32 + quad * 8];
            #pragma unroll
            for (int jt = 0; jt < 4; jt++)
                bb[jt] = *(const bf16x8*)&Ks[(jt * 16 + ln) * LDP + ks * 32 + quad * 8];
            #pragma unroll
            for (int rt = 0; rt < 2; rt++)
                #pragma unroll
                for (int jt = 0; jt < 4; jt++)
                    s[rt][jt] = __builtin_amdgcn_mfma_f32_16x16x32_bf16(a[rt], bb[jt], s[rt][jt], 0, 0, 0);
        }

        // online softmax per row; row r lives on the 16 lanes of this quad group
        #pragma unroll
        for (int rt = 0; rt < 2; rt++) {
            #pragma unroll
            for (int r = 0; r < 4; r++) {
                float mx = fmaxf(fmaxf(s[rt][0][r], s[rt][1][r]), fmaxf(s[rt][2][r], s[rt][3][r]));
                mx = fmaxf(mx, __shfl_xor(mx, 1));
                mx = fmaxf(mx, __shfl_xor(mx, 2));
                mx = fmaxf(mx, __shfl_xor(mx, 4));
                mx = fmaxf(mx, __shfl_xor(mx, 8));
                mx *= scale;
                float m_new = fmaxf(m_i[rt][r], mx);
                float alpha = __expf(m_i[rt][r] - m_new);
                m_i[rt][r] = m_new;
                float rs = 0.0f;
                #pragma unroll
                for (int jt = 0; jt < 4; jt++) {
                    float p = __expf(s[rt][jt][r] * scale - m_new);
                    Ps[(wave * 32 + rt * 16 + quad * 4 + r) * LDP + jt * 16 + ln] = (__bf16)p;
                    rs += p;
                }
                rs += __shfl_xor(rs, 1);
                rs += __shfl_xor(rs, 2);
                rs += __shfl_xor(rs, 4);
                rs += __shfl_xor(rs, 8);
                l_i[rt][r] = l_i[rt][r] * alpha + rs;
                #pragma unroll
                for (int dt = 0; dt < 4; dt++) o_acc[rt][dt][r] *= alpha;
            }
        }
        __syncthreads();  // belt-and-suspenders for the Ps LDS round-trip (per-wave; try removing later)

        #pragma unroll
        for (int ks = 0; ks < 2; ks++) {
            bf16x8 a[2], bb[4];
            a[0] = *(const bf16x8*)&Ps[(wave * 32 + ln) * LDP + ks * 32 + quad * 8];
            a[1] = *(const bf16x8*)&Ps[(wave * 32 + 16 + ln) * LDP + ks * 32 + quad * 8];
            #pragma unroll
            for (int dt = 0; dt < 4; dt++)
                bb[dt] = *(const bf16x8*)&VTs[(dt * 16 + ln) * LDP + ks * 32 + quad * 8];
            #pragma unroll
            for (int rt = 0; rt < 2; rt++)
                #pragma unroll
                for (int dt = 0; dt < 4; dt++)
                    o_acc[rt][dt] = __builtin_amdgcn_mfma_f32_16x16x32_bf16(a[rt], bb[dt], o_acc[rt][dt], 0, 0, 0);
        }
    }

    #pragma unroll
    for (int rt = 0; rt < 2; rt++) {
        const int row = q0 + wave * 32 + rt * 16 + quad * 4;
        #pragma unroll
        for (int r = 0; r < 4; r++) {
            float inv = 1.0f / l_i[rt][r];
            #pragma unroll
            for (int dt = 0; dt < 4; dt++)
                Og[base + (row + r) * 1024 + dt * 16 + ln] = (__bf16)(o_acc[rt][dt][r] * inv);
        }
    }
}

// ---------------------------------------------------------------------------
extern "C" void kernel_launch(void* const* d_in, const int* in_sizes, int n_in,
                              void* d_out, int out_size, void* d_ws, size_t ws_size,
                              hipStream_t stream)
{
    // ws layout: [0,4) flag; cv = ws+256 holds bf16 copies of all inputs, then
    // zb / Q / K / V; O reuses the (dead after proj1) z-copy region. ~72 MB total.
    int* flag = (int*)d_ws;
    __bf16* cv = (__bf16*)((char*)d_ws + 256);

    const int Z = 0, WQ = 8388608, WK = 8454144, WV = 8519680;
    const int FCQW = 8585216, FCKW = 8650752, FCVW = 8716288, FCOW = 8781824;
    const int FCQB = 9830400, FCKB = 9831424, FCVB = 9832448, FCOB = 9833472;
    __bf16* zb = cv + 10485760;            // 3 x 524288
    __bf16* Qw = cv + 12582912;            // 8388608 each
    __bf16* Kw = Qw + 8388608;
    __bf16* Vw = Kw + 8388608;
    __bf16* Ow = cv + Z;                   // reuse z-copy region (dead after proj1)

    detect_dtype<<<1, 256, 0, stream>>>((const unsigned short*)d_in[0], flag);

    ConvArgs ca;
    const int offs[12] = {Z, WQ, WK, WV, FCQW, FCQB, FCKW, FCKB, FCVW, FCVB, FCOW, FCOB};
    for (int i = 0; i < 12; i++) { ca.src[i] = d_in[i]; ca.n[i] = in_sizes[i]; ca.off[i] = offs[i]; }
    convert_inputs<<<dim3(4096, 12), 256, 0, stream>>>(ca, cv, flag);

    // 1) zb_{q,k,v} = z @ w_{q,k,v}   [8192,1024]@[1024,64]
    gemm_bias<<<dim3(64, 1, 3), 256, 0, stream>>>(
        cv + Z, cv + Z, cv + Z, cv + WQ, cv + WK, cv + WV,
        cv + FCQB, cv + FCQB, cv + FCQB,
        zb, zb + 524288, zb + 1048576, 8192, 64, 1024, 0, nullptr);

    // 2) Q/K/V = zb @ fc_w + fc_b    [8192,64]@[64,1024]
    gemm_bias<<<dim3(64, 16, 3), 256, 0, stream>>>(
        zb, zb + 524288, zb + 1048576,
        cv + FCQW, cv + FCKW, cv + FCVW, cv + FCQB, cv + FCKB, cv + FCVB,
        Qw, Kw, Vw, 8192, 1024, 64, 1, nullptr);

    // 3) flash attention
    attn_kernel<<<dim3(16, 64), 256, 0, stream>>>(Qw, Kw, Vw, Ow);

    // 4) out = O @ fco_w + fco_b     [8192,1024]@[1024,1024]; dtype per flag
    gemm_bias<<<dim3(64, 16, 1), 256, 0, stream>>>(
        Ow, Ow, Ow, cv + FCOW, cv + FCOW, cv + FCOW, cv + FCOB, cv + FCOB, cv + FCOB,
        d_out, d_out, d_out, 8192, 1024, 1024, 1, flag);
}

// Round 3
// 444.953 us; speedup vs baseline: 1.2074x; 1.2074x over previous
//
#include <hip/hip_runtime.h>

// multi_SelfAttention on MI355X (gfx950). Inputs arrive fp32 (detected at
// runtime for robustness); converted to bf16, compute in bf16 MFMA, output
// dtype per flag. Pipeline: convert -> proj1 -> proj2 -> flash attn -> proj3.

typedef __bf16 bf16x8 __attribute__((ext_vector_type(8)));
typedef float floatx4 __attribute__((ext_vector_type(4)));

#define LDP 72  // padded LDS row stride (bf16): 144 B, breaks pow2 banks

// ---------------------------------------------------------------------------
// Dtype detector: fp32 data read as bf16 pairs shows ~35% weird exponents.
// ---------------------------------------------------------------------------
__global__ void detect_dtype(const unsigned short* __restrict__ z, int* __restrict__ flag) {
    __shared__ int cnt;
    if (threadIdx.x == 0) cnt = 0;
    __syncthreads();
    int local = 0;
    for (int i = threadIdx.x; i < 16384; i += 256) {
        unsigned int u = (unsigned int)z[i] << 16;
        float x = __uint_as_float(u);
        float ax = fabsf(x);
        if (!(ax <= 1024.0f) || (x != 0.0f && ax < 1e-20f)) local++;
    }
    atomicAdd(&cnt, local);
    __syncthreads();
    if (threadIdx.x == 0) *flag = (cnt > 1310) ? 1 : 0;
}

// ---------------------------------------------------------------------------
struct ConvArgs { const void* src[12]; int n[12]; int off[12]; };

__global__ void convert_inputs(ConvArgs a, __bf16* __restrict__ cv, const int* __restrict__ flag) {
    const int k = blockIdx.y;
    const int i = (blockIdx.x * 256 + threadIdx.x) * 8;
    if (i >= a.n[k]) return;
    __bf16* dst = cv + a.off[k] + i;
    if (*flag) {
        const float* s = (const float*)a.src[k] + i;
        float4 f0 = *(const float4*)s;
        float4 f1 = *(const float4*)(s + 4);
        bf16x8 v;
        v[0] = (__bf16)f0.x; v[1] = (__bf16)f0.y; v[2] = (__bf16)f0.z; v[3] = (__bf16)f0.w;
        v[4] = (__bf16)f1.x; v[5] = (__bf16)f1.y; v[6] = (__bf16)f1.z; v[7] = (__bf16)f1.w;
        *(bf16x8*)dst = v;
    } else {
        *(bf16x8*)dst = *(const bf16x8*)((const __bf16*)a.src[k] + i);
    }
}

// ---------------------------------------------------------------------------
// Generic tiled GEMM: C[M,N] = A[M,K] @ B[K,N] (+ bias), bf16 in, fp32 acc.
// ---------------------------------------------------------------------------
__global__ __launch_bounds__(256) void gemm_bias(
    const __bf16* __restrict__ A0, const __bf16* __restrict__ A1, const __bf16* __restrict__ A2,
    const __bf16* __restrict__ B0, const __bf16* __restrict__ B1, const __bf16* __restrict__ B2,
    const __bf16* __restrict__ bias0, const __bf16* __restrict__ bias1, const __bf16* __restrict__ bias2,
    void* __restrict__ C0, void* __restrict__ C1, void* __restrict__ C2,
    int M, int N, int K, int has_bias, const int* flagp)
{
    const int zsel = blockIdx.z;
    const __bf16* A = (zsel == 0) ? A0 : (zsel == 1) ? A1 : A2;
    const __bf16* B = (zsel == 0) ? B0 : (zsel == 1) ? B1 : B2;
    const __bf16* bias = (zsel == 0) ? bias0 : (zsel == 1) ? bias1 : bias2;
    void* C = (zsel == 0) ? C0 : (zsel == 1) ? C1 : C2;
    const int out_fp32 = flagp ? *flagp : 0;

    const int m0 = blockIdx.x * 128;
    const int n0 = blockIdx.y * 64;
    const int tid = threadIdx.x;
    const int wave = tid >> 6;
    const int ln = tid & 15;
    const int quad = (tid >> 4) & 3;

    __shared__ __bf16 As[128 * LDP];
    __shared__ __bf16 Bts[64 * LDP];

    floatx4 acc[2][4] = {};

    for (int k0 = 0; k0 < K; k0 += 64) {
        __syncthreads();
        for (int i = tid; i < 1024; i += 256) {
            int r = i >> 3, c8 = (i & 7) << 3;
            *(bf16x8*)&As[r * LDP + c8] = *(const bf16x8*)&A[(m0 + r) * K + k0 + c8];
        }
        for (int i = tid; i < 512; i += 256) {
            int kk = i >> 3, nn0 = (i & 7) << 3;
            bf16x8 v = *(const bf16x8*)&B[(k0 + kk) * N + n0 + nn0];
            #pragma unroll
            for (int j = 0; j < 8; j++) Bts[(nn0 + j) * LDP + kk] = v[j];
        }
        __syncthreads();
        #pragma unroll
        for (int ks = 0; ks < 2; ks++) {
            bf16x8 a[2], b[4];
            a[0] = *(const bf16x8*)&As[(wave * 32 + ln) * LDP + ks * 32 + quad * 8];
            a[1] = *(const bf16x8*)&As[(wave * 32 + 16 + ln) * LDP + ks * 32 + quad * 8];
            #pragma unroll
            for (int nt = 0; nt < 4; nt++)
                b[nt] = *(const bf16x8*)&Bts[(nt * 16 + ln) * LDP + ks * 32 + quad * 8];
            #pragma unroll
            for (int rt = 0; rt < 2; rt++)
                #pragma unroll
                for (int nt = 0; nt < 4; nt++)
                    acc[rt][nt] = __builtin_amdgcn_mfma_f32_16x16x32_bf16(a[rt], b[nt], acc[rt][nt], 0, 0, 0);
        }
    }
    #pragma unroll
    for (int rt = 0; rt < 2; rt++) {
        const int row = m0 + wave * 32 + rt * 16 + quad * 4;
        #pragma unroll
        for (int nt = 0; nt < 4; nt++) {
            const int col = n0 + nt * 16 + ln;
            float bv = has_bias ? (float)bias[col] : 0.0f;
            #pragma unroll
            for (int r = 0; r < 4; r++) {
                float val = acc[rt][nt][r] + bv;
                if (out_fp32) ((float*)C)[(row + r) * N + col] = val;
                else ((__bf16*)C)[(row + r) * N + col] = (__bf16)val;
            }
        }
    }
}

// ---------------------------------------------------------------------------
// Flash attention, round-3 rework:
//  - Q fragments in registers (pre-scaled by 1/8, exact in bf16)
//  - double-buffered K/V tiles, ONE barrier per kv tile
//  - V-transpose scatter remapped (consecutive r across lanes: conflict-free)
//  - Ps: stride 64 + XOR swizzle (col ^ (rowquad<<4)): conflict-free stores,
//    16B-aligned b128 reads at the 8-pass minimum
//  - LDS 52 KB -> 3 blocks/CU
// ---------------------------------------------------------------------------
#define PSWZ(row, col) (((row) << 6) + ((col) ^ ((((row) >> 2) & 3) << 4)))

__global__ __launch_bounds__(256, 3) void attn_kernel(
    const __bf16* __restrict__ Qg, const __bf16* __restrict__ Kg,
    const __bf16* __restrict__ Vg, __bf16* __restrict__ Og)
{
    const int bh = blockIdx.y;
    const int b = bh >> 4, h = bh & 15;
    const int q0 = blockIdx.x * 128;
    const int base = b * 2048 * 1024 + h * 64;
    const int tid = threadIdx.x;
    const int wave = tid >> 6, ln = tid & 15, quad = (tid >> 4) & 3;

    __shared__ __bf16 Ks[2][64 * LDP];
    __shared__ __bf16 VTs[2][64 * LDP];
    __shared__ __bf16 Ps[128 * 64];      // swizzled

    // Q fragments in registers, pre-scaled by 1/sqrt(64)=0.125 (exact pow2)
    bf16x8 qf[2][2];  // [rt][ks]
    #pragma unroll
    for (int rt = 0; rt < 2; rt++)
        #pragma unroll
        for (int ks = 0; ks < 2; ks++) {
            bf16x8 v = *(const bf16x8*)&Qg[base + (q0 + wave * 32 + rt * 16 + ln) * 1024 + ks * 32 + quad * 8];
            #pragma unroll
            for (int j = 0; j < 8; j++) v[j] = (__bf16)((float)v[j] * 0.125f);
            qf[rt][ks] = v;
        }

    // staging index maps
    const int kr = tid >> 3, kc = (tid & 7) << 3;   // K: 8 lanes/row, coalesced
    const int vr = tid & 63, vc = (tid >> 6) << 3;  // V: consecutive r across lanes

    // preload tile 0
    {
        bf16x8 ka = *(const bf16x8*)&Kg[base + (kr) * 1024 + kc];
        bf16x8 kb = *(const bf16x8*)&Kg[base + (kr + 32) * 1024 + kc];
        bf16x8 va = *(const bf16x8*)&Vg[base + (vr) * 1024 + vc];
        bf16x8 vb = *(const bf16x8*)&Vg[base + (vr) * 1024 + vc + 32];
        *(bf16x8*)&Ks[0][kr * LDP + kc] = ka;
        *(bf16x8*)&Ks[0][(kr + 32) * LDP + kc] = kb;
        #pragma unroll
        for (int j = 0; j < 8; j++) {
            VTs[0][(vc + j) * LDP + vr] = va[j];
            VTs[0][(vc + 32 + j) * LDP + vr] = vb[j];
        }
    }

    floatx4 o_acc[2][4] = {};
    float m_i[2][4], l_i[2][4];
    #pragma unroll
    for (int rt = 0; rt < 2; rt++)
        #pragma unroll
        for (int r = 0; r < 4; r++) { m_i[rt][r] = -1e30f; l_i[rt][r] = 0.0f; }

    for (int t = 0; t < 32; t++) {
        const int cur = t & 1;
        bf16x8 ka, kb, va, vb;
        if (t < 31) {
            const int kvn = (t + 1) * 64;
            ka = *(const bf16x8*)&Kg[base + (kvn + kr) * 1024 + kc];
            kb = *(const bf16x8*)&Kg[base + (kvn + kr + 32) * 1024 + kc];
            va = *(const bf16x8*)&Vg[base + (kvn + vr) * 1024 + vc];
            vb = *(const bf16x8*)&Vg[base + (kvn + vr) * 1024 + vc + 32];
        }
        __syncthreads();  // buf[cur] fully staged; prior reads of buf[cur^1] drained

        // S = Qs @ K^T  (Q pre-scaled)
        floatx4 s[2][4] = {};
        #pragma unroll
        for (int ks = 0; ks < 2; ks++) {
            bf16x8 bb[4];
            #pragma unroll
            for (int jt = 0; jt < 4; jt++)
                bb[jt] = *(const bf16x8*)&Ks[cur][(jt * 16 + ln) * LDP + ks * 32 + quad * 8];
            #pragma unroll
            for (int rt = 0; rt < 2; rt++)
                #pragma unroll
                for (int jt = 0; jt < 4; jt++)
                    s[rt][jt] = __builtin_amdgcn_mfma_f32_16x16x32_bf16(qf[rt][ks], bb[jt], s[rt][jt], 0, 0, 0);
        }

        // online softmax; P into swizzled Ps (per-wave region, in-order DS)
        #pragma unroll
        for (int rt = 0; rt < 2; rt++) {
            #pragma unroll
            for (int r = 0; r < 4; r++) {
                float mx = fmaxf(fmaxf(s[rt][0][r], s[rt][1][r]), fmaxf(s[rt][2][r], s[rt][3][r]));
                mx = fmaxf(mx, __shfl_xor(mx, 1));
                mx = fmaxf(mx, __shfl_xor(mx, 2));
                mx = fmaxf(mx, __shfl_xor(mx, 4));
                mx = fmaxf(mx, __shfl_xor(mx, 8));
                float m_new = fmaxf(m_i[rt][r], mx);
                float alpha = __expf(m_i[rt][r] - m_new);
                m_i[rt][r] = m_new;
                const int row = wave * 32 + rt * 16 + quad * 4 + r;
                float rs = 0.0f;
                #pragma unroll
                for (int jt = 0; jt < 4; jt++) {
                    float p = __expf(s[rt][jt][r] - m_new);
                    Ps[PSWZ(row, jt * 16 + ln)] = (__bf16)p;
                    rs += p;
                }
                rs += __shfl_xor(rs, 1);
                rs += __shfl_xor(rs, 2);
                rs += __shfl_xor(rs, 4);
                rs += __shfl_xor(rs, 8);
                l_i[rt][r] = l_i[rt][r] * alpha + rs;
                #pragma unroll
                for (int dt = 0; dt < 4; dt++) o_acc[rt][dt][r] *= alpha;
            }
        }

        // O += P @ V
        #pragma unroll
        for (int ks = 0; ks < 2; ks++) {
            bf16x8 a[2], bb[4];
            #pragma unroll
            for (int rt = 0; rt < 2; rt++) {
                const int row = wave * 32 + rt * 16 + ln;
                a[rt] = *(const bf16x8*)&Ps[PSWZ(row, ks * 32 + quad * 8)];
            }
            #pragma unroll
            for (int dt = 0; dt < 4; dt++)
                bb[dt] = *(const bf16x8*)&VTs[cur][(dt * 16 + ln) * LDP + ks * 32 + quad * 8];
            #pragma unroll
            for (int rt = 0; rt < 2; rt++)
                #pragma unroll
                for (int dt = 0; dt < 4; dt++)
                    o_acc[rt][dt] = __builtin_amdgcn_mfma_f32_16x16x32_bf16(a[rt], bb[dt], o_acc[rt][dt], 0, 0, 0);
        }

        // stage tile t+1 into the other buffer (after compute; before next barrier)
        if (t < 31) {
            const int nxt = cur ^ 1;
            *(bf16x8*)&Ks[nxt][kr * LDP + kc] = ka;
            *(bf16x8*)&Ks[nxt][(kr + 32) * LDP + kc] = kb;
            #pragma unroll
            for (int j = 0; j < 8; j++) {
                VTs[nxt][(vc + j) * LDP + vr] = va[j];
                VTs[nxt][(vc + 32 + j) * LDP + vr] = vb[j];
            }
        }
    }

    #pragma unroll
    for (int rt = 0; rt < 2; rt++) {
        const int row = q0 + wave * 32 + rt * 16 + quad * 4;
        #pragma unroll
        for (int r = 0; r < 4; r++) {
            float inv = 1.0f / l_i[rt][r];
            #pragma unroll
            for (int dt = 0; dt < 4; dt++)
                Og[base + (row + r) * 1024 + dt * 16 + ln] = (__bf16)(o_acc[rt][dt][r] * inv);
        }
    }
}

// ---------------------------------------------------------------------------
extern "C" void kernel_launch(void* const* d_in, const int* in_sizes, int n_in,
                              void* d_out, int out_size, void* d_ws, size_t ws_size,
                              hipStream_t stream)
{
    int* flag = (int*)d_ws;
    __bf16* cv = (__bf16*)((char*)d_ws + 256);

    const int Z = 0, WQ = 8388608, WK = 8454144, WV = 8519680;
    const int FCQW = 8585216, FCKW = 8650752, FCVW = 8716288, FCOW = 8781824;
    const int FCQB = 9830400, FCKB = 9831424, FCVB = 9832448, FCOB = 9833472;
    __bf16* zb = cv + 10485760;
    __bf16* Qw = cv + 12582912;
    __bf16* Kw = Qw + 8388608;
    __bf16* Vw = Kw + 8388608;
    __bf16* Ow = cv + Z;  // reuse z-copy region (dead after proj1)

    detect_dtype<<<1, 256, 0, stream>>>((const unsigned short*)d_in[0], flag);

    ConvArgs ca;
    const int offs[12] = {Z, WQ, WK, WV, FCQW, FCQB, FCKW, FCKB, FCVW, FCVB, FCOW, FCOB};
    for (int i = 0; i < 12; i++) { ca.src[i] = d_in[i]; ca.n[i] = in_sizes[i]; ca.off[i] = offs[i]; }
    convert_inputs<<<dim3(4096, 12), 256, 0, stream>>>(ca, cv, flag);

    gemm_bias<<<dim3(64, 1, 3), 256, 0, stream>>>(
        cv + Z, cv + Z, cv + Z, cv + WQ, cv + WK, cv + WV,
        cv + FCQB, cv + FCQB, cv + FCQB,
        zb, zb + 524288, zb + 1048576, 8192, 64, 1024, 0, nullptr);

    gemm_bias<<<dim3(64, 16, 3), 256, 0, stream>>>(
        zb, zb + 524288, zb + 1048576,
        cv + FCQW, cv + FCKW, cv + FCVW, cv + FCQB, cv + FCKB, cv + FCVB,
        Qw, Kw, Vw, 8192, 1024, 64, 1, nullptr);

    attn_kernel<<<dim3(16, 64), 256, 0, stream>>>(Qw, Kw, Vw, Ow);

    gemm_bias<<<dim3(64, 16, 1), 256, 0, stream>>>(
        Ow, Ow, Ow, cv + FCOW, cv + FCOW, cv + FCOW, cv + FCOB, cv + FCOB, cv + FCOB,
        d_out, d_out, d_out, 8192, 1024, 1024, 1, flag);
}

// Round 5
// 400.875 us; speedup vs baseline: 1.3402x; 1.1100x over previous
//
#include <hip/hip_runtime.h>

// multi_SelfAttention on MI355X (gfx950). Inputs arrive fp32 (runtime-detected);
// converted to bf16, compute in bf16 MFMA, output dtype per flag.
// Pipeline: convert -> proj1 -> proj2 (Q pre-scaled by 0.125*log2e) ->
//           flash attn (log2-domain softmax) -> proj3.

typedef __bf16 bf16x8 __attribute__((ext_vector_type(8)));
typedef float floatx4 __attribute__((ext_vector_type(4)));

#define LDP 72  // padded LDS row stride (bf16): 144 B -> row adds 4 banks

#if __has_builtin(__builtin_amdgcn_exp2f)
__device__ __forceinline__ float fast_exp2(float x) { return __builtin_amdgcn_exp2f(x); }
#else
__device__ __forceinline__ float fast_exp2(float x) { return exp2f(x); }
#endif

// 16-lane (DPP-row) reductions; our S-row lanes are exactly one DPP row.
// DPP ctrl must be a compile-time constant -> template parameter.
template <int CTRL>
__device__ __forceinline__ float dpp_bcast(float x) {
    return __int_as_float(__builtin_amdgcn_update_dpp(0, __float_as_int(x), CTRL, 0xF, 0xF, false));
}
__device__ __forceinline__ float red16_max(float x) {
    x = fmaxf(x, dpp_bcast<0xB1>(x));   // quad_perm [1,0,3,2]
    x = fmaxf(x, dpp_bcast<0x4E>(x));   // quad_perm [2,3,0,1]
    x = fmaxf(x, dpp_bcast<0x141>(x));  // row_half_mirror
    x = fmaxf(x, dpp_bcast<0x140>(x));  // row_mirror
    return x;
}
__device__ __forceinline__ float red16_sum(float x) {
    x += dpp_bcast<0xB1>(x);
    x += dpp_bcast<0x4E>(x);
    x += dpp_bcast<0x141>(x);
    x += dpp_bcast<0x140>(x);
    return x;
}

// ---------------------------------------------------------------------------
__global__ void detect_dtype(const unsigned short* __restrict__ z, int* __restrict__ flag) {
    __shared__ int cnt;
    if (threadIdx.x == 0) cnt = 0;
    __syncthreads();
    int local = 0;
    for (int i = threadIdx.x; i < 16384; i += 256) {
        unsigned int u = (unsigned int)z[i] << 16;
        float x = __uint_as_float(u);
        float ax = fabsf(x);
        if (!(ax <= 1024.0f) || (x != 0.0f && ax < 1e-20f)) local++;
    }
    atomicAdd(&cnt, local);
    __syncthreads();
    if (threadIdx.x == 0) *flag = (cnt > 1310) ? 1 : 0;
}

// ---------------------------------------------------------------------------
struct ConvArgs { const void* src[12]; int n[12]; int off[12]; };

__global__ void convert_inputs(ConvArgs a, __bf16* __restrict__ cv, const int* __restrict__ flag) {
    const int k = blockIdx.y;
    const int i = (blockIdx.x * 256 + threadIdx.x) * 8;
    if (i >= a.n[k]) return;
    __bf16* dst = cv + a.off[k] + i;
    if (*flag) {
        const float* s = (const float*)a.src[k] + i;
        float4 f0 = *(const float4*)s;
        float4 f1 = *(const float4*)(s + 4);
        bf16x8 v;
        v[0] = (__bf16)f0.x; v[1] = (__bf16)f0.y; v[2] = (__bf16)f0.z; v[3] = (__bf16)f0.w;
        v[4] = (__bf16)f1.x; v[5] = (__bf16)f1.y; v[6] = (__bf16)f1.z; v[7] = (__bf16)f1.w;
        *(bf16x8*)dst = v;
    } else {
        *(bf16x8*)dst = *(const bf16x8*)((const __bf16*)a.src[k] + i);
    }
}

// ---------------------------------------------------------------------------
// Tiled GEMM: C[M,N] = (A[M,K] @ B[K,N] + bias) * out_scale, bf16 in, fp32 acc.
// B^T staging: lane = k-row (uncoalesced global, L2-resident weights),
// wave = n-chunk -> each LDS scatter instr writes 64 consecutive elems (conflict-free).
// ---------------------------------------------------------------------------
__global__ __launch_bounds__(256) void gemm_bias(
    const __bf16* __restrict__ A0, const __bf16* __restrict__ A1, const __bf16* __restrict__ A2,
    const __bf16* __restrict__ B0, const __bf16* __restrict__ B1, const __bf16* __restrict__ B2,
    const __bf16* __restrict__ bias0, const __bf16* __restrict__ bias1, const __bf16* __restrict__ bias2,
    void* __restrict__ C0, void* __restrict__ C1, void* __restrict__ C2,
    int M, int N, int K, int has_bias, const int* flagp,
    float os0, float os1, float os2)
{
    const int zsel = blockIdx.z;
    const __bf16* A = (zsel == 0) ? A0 : (zsel == 1) ? A1 : A2;
    const __bf16* B = (zsel == 0) ? B0 : (zsel == 1) ? B1 : B2;
    const __bf16* bias = (zsel == 0) ? bias0 : (zsel == 1) ? bias1 : bias2;
    void* C = (zsel == 0) ? C0 : (zsel == 1) ? C1 : C2;
    const float oscale = (zsel == 0) ? os0 : (zsel == 1) ? os1 : os2;
    const int out_fp32 = flagp ? *flagp : 0;

    const int m0 = blockIdx.x * 128;
    const int n0 = blockIdx.y * 64;
    const int tid = threadIdx.x;
    const int wave = tid >> 6;
    const int ln = tid & 15;
    const int quad = (tid >> 4) & 3;

    __shared__ __bf16 As[128 * LDP];
    __shared__ __bf16 Bts[64 * LDP];

    const int bkr = tid & 63;          // k row within tile
    const int bnc = (tid >> 6) << 3;   // n chunk base (8 per wave)

    floatx4 acc[2][4] = {};

    for (int k0 = 0; k0 < K; k0 += 64) {
        __syncthreads();
        for (int i = tid; i < 1024; i += 256) {
            int r = i >> 3, c8 = (i & 7) << 3;
            *(bf16x8*)&As[r * LDP + c8] = *(const bf16x8*)&A[(m0 + r) * K + k0 + c8];
        }
        {
            bf16x8 b0 = *(const bf16x8*)&B[(k0 + bkr) * N + n0 + bnc];
            bf16x8 b1 = *(const bf16x8*)&B[(k0 + bkr) * N + n0 + bnc + 32];
            #pragma unroll
            for (int j = 0; j < 8; j++) {
                Bts[(bnc + j) * LDP + bkr] = b0[j];        // 64 consecutive elems/instr
                Bts[(bnc + 32 + j) * LDP + bkr] = b1[j];
            }
        }
        __syncthreads();
        #pragma unroll
        for (int ks = 0; ks < 2; ks++) {
            bf16x8 a[2], b[4];
            a[0] = *(const bf16x8*)&As[(wave * 32 + ln) * LDP + ks * 32 + quad * 8];
            a[1] = *(const bf16x8*)&As[(wave * 32 + 16 + ln) * LDP + ks * 32 + quad * 8];
            #pragma unroll
            for (int nt = 0; nt < 4; nt++)
                b[nt] = *(const bf16x8*)&Bts[(nt * 16 + ln) * LDP + ks * 32 + quad * 8];
            #pragma unroll
            for (int rt = 0; rt < 2; rt++)
                #pragma unroll
                for (int nt = 0; nt < 4; nt++)
                    acc[rt][nt] = __builtin_amdgcn_mfma_f32_16x16x32_bf16(a[rt], b[nt], acc[rt][nt], 0, 0, 0);
        }
    }
    #pragma unroll
    for (int rt = 0; rt < 2; rt++) {
        const int row = m0 + wave * 32 + rt * 16 + quad * 4;
        #pragma unroll
        for (int nt = 0; nt < 4; nt++) {
            const int col = n0 + nt * 16 + ln;
            float bv = has_bias ? (float)bias[col] : 0.0f;
            #pragma unroll
            for (int r = 0; r < 4; r++) {
                float val = (acc[rt][nt][r] + bv) * oscale;
                if (out_fp32) ((float*)C)[(row + r) * N + col] = val;
                else ((__bf16*)C)[(row + r) * N + col] = (__bf16)val;
            }
        }
    }
}

// ---------------------------------------------------------------------------
// Flash attention. Q arrives pre-scaled by 0.125*log2(e) (folded into proj2),
// so softmax runs in the log2 domain: p = exp2(s - m).
// Ps swizzle: w(row) = (row&7) ^ (((row>>3)&1)<<1); chunk' = chunk ^ w.
//   reads  (row=..+ln, chunk fixed): w bijects ln&7 -> 8 windows/8-lane phase, free
//   stores (row=..quad*4+r, col=jt*16+ln): (ln3,quad)<->chunk' bijective -> 32 banks x2, free
// ---------------------------------------------------------------------------
#define PSW(row, col) (((row) << 6) | (((((col) >> 3) ^ (((row) & 7) ^ ((((row) >> 3) & 1) << 1))) << 3) | ((col) & 7)))

__global__ __launch_bounds__(256, 3) void attn_kernel(
    const __bf16* __restrict__ Qg, const __bf16* __restrict__ Kg,
    const __bf16* __restrict__ Vg, __bf16* __restrict__ Og)
{
    const int bh = blockIdx.y;
    const int b = bh >> 4, h = bh & 15;
    const int q0 = blockIdx.x * 128;
    const int base = b * 2048 * 1024 + h * 64;
    const int tid = threadIdx.x;
    const int wave = tid >> 6, ln = tid & 15, quad = (tid >> 4) & 3;

    __shared__ __bf16 Ks[2][64 * LDP];
    __shared__ __bf16 VTs[2][64 * LDP];
    __shared__ __bf16 Ps[128 * 64];      // swizzled via PSW

    // Q fragments in registers (already scaled by 0.125*log2e in proj2)
    bf16x8 qf[2][2];
    #pragma unroll
    for (int rt = 0; rt < 2; rt++)
        #pragma unroll
        for (int ks = 0; ks < 2; ks++)
            qf[rt][ks] = *(const bf16x8*)&Qg[base + (q0 + wave * 32 + rt * 16 + ln) * 1024 + ks * 32 + quad * 8];

    const int kr = tid >> 3, kc = (tid & 7) << 3;   // K staging: coalesced rows
    const int vr = tid & 63, vc = (tid >> 6) << 3;  // V staging: lane = row (scatter-free)

    {
        bf16x8 ka = *(const bf16x8*)&Kg[base + (kr) * 1024 + kc];
        bf16x8 kb = *(const bf16x8*)&Kg[base + (kr + 32) * 1024 + kc];
        bf16x8 va = *(const bf16x8*)&Vg[base + (vr) * 1024 + vc];
        bf16x8 vb = *(const bf16x8*)&Vg[base + (vr) * 1024 + vc + 32];
        *(bf16x8*)&Ks[0][kr * LDP + kc] = ka;
        *(bf16x8*)&Ks[0][(kr + 32) * LDP + kc] = kb;
        #pragma unroll
        for (int j = 0; j < 8; j++) {
            VTs[0][(vc + j) * LDP + vr] = va[j];
            VTs[0][(vc + 32 + j) * LDP + vr] = vb[j];
        }
    }

    floatx4 o_acc[2][4] = {};
    float m_i[2][4], l_i[2][4];
    #pragma unroll
    for (int rt = 0; rt < 2; rt++)
        #pragma unroll
        for (int r = 0; r < 4; r++) { m_i[rt][r] = -1e30f; l_i[rt][r] = 0.0f; }

    for (int t = 0; t < 32; t++) {
        const int cur = t & 1;
        bf16x8 ka, kb, va, vb;
        if (t < 31) {
            const int kvn = (t + 1) * 64;
            ka = *(const bf16x8*)&Kg[base + (kvn + kr) * 1024 + kc];
            kb = *(const bf16x8*)&Kg[base + (kvn + kr + 32) * 1024 + kc];
            va = *(const bf16x8*)&Vg[base + (kvn + vr) * 1024 + vc];
            vb = *(const bf16x8*)&Vg[base + (kvn + vr) * 1024 + vc + 32];
        }
        __syncthreads();

        // S = Qs @ K^T  (log2-domain scores)
        floatx4 s[2][4] = {};
        #pragma unroll
        for (int ks = 0; ks < 2; ks++) {
            bf16x8 bb[4];
            #pragma unroll
            for (int jt = 0; jt < 4; jt++)
                bb[jt] = *(const bf16x8*)&Ks[cur][(jt * 16 + ln) * LDP + ks * 32 + quad * 8];
            #pragma unroll
            for (int rt = 0; rt < 2; rt++)
                #pragma unroll
                for (int jt = 0; jt < 4; jt++)
                    s[rt][jt] = __builtin_amdgcn_mfma_f32_16x16x32_bf16(qf[rt][ks], bb[jt], s[rt][jt], 0, 0, 0);
        }

        // online softmax (base-2); DPP 16-lane reductions
        #pragma unroll
        for (int rt = 0; rt < 2; rt++) {
            #pragma unroll
            for (int r = 0; r < 4; r++) {
                float mx = fmaxf(fmaxf(s[rt][0][r], s[rt][1][r]), fmaxf(s[rt][2][r], s[rt][3][r]));
                mx = red16_max(mx);
                float m_new = fmaxf(m_i[rt][r], mx);
                float alpha = fast_exp2(m_i[rt][r] - m_new);
                m_i[rt][r] = m_new;
                const int row = wave * 32 + rt * 16 + quad * 4 + r;
                float rs = 0.0f;
                #pragma unroll
                for (int jt = 0; jt < 4; jt++) {
                    float p = fast_exp2(s[rt][jt][r] - m_new);
                    Ps[PSW(row, jt * 16 + ln)] = (__bf16)p;
                    rs += p;
                }
                rs = red16_sum(rs);
                l_i[rt][r] = l_i[rt][r] * alpha + rs;
                #pragma unroll
                for (int dt = 0; dt < 4; dt++) o_acc[rt][dt][r] *= alpha;
            }
        }

        // O += P @ V  (same-wave LDS RAW: DS in-order, no barrier)
        #pragma unroll
        for (int ks = 0; ks < 2; ks++) {
            bf16x8 a[2], bb[4];
            #pragma unroll
            for (int rt = 0; rt < 2; rt++) {
                const int row = wave * 32 + rt * 16 + ln;
                a[rt] = *(const bf16x8*)&Ps[PSW(row, ks * 32 + quad * 8)];
            }
            #pragma unroll
            for (int dt = 0; dt < 4; dt++)
                bb[dt] = *(const bf16x8*)&VTs[cur][(dt * 16 + ln) * LDP + ks * 32 + quad * 8];
            #pragma unroll
            for (int rt = 0; rt < 2; rt++)
                #pragma unroll
                for (int dt = 0; dt < 4; dt++)
                    o_acc[rt][dt] = __builtin_amdgcn_mfma_f32_16x16x32_bf16(a[rt], bb[dt], o_acc[rt][dt], 0, 0, 0);
        }

        if (t < 31) {
            const int nxt = cur ^ 1;
            *(bf16x8*)&Ks[nxt][kr * LDP + kc] = ka;
            *(bf16x8*)&Ks[nxt][(kr + 32) * LDP + kc] = kb;
            #pragma unroll
            for (int j = 0; j < 8; j++) {
                VTs[nxt][(vc + j) * LDP + vr] = va[j];
                VTs[nxt][(vc + 32 + j) * LDP + vr] = vb[j];
            }
        }
    }

    #pragma unroll
    for (int rt = 0; rt < 2; rt++) {
        const int row = q0 + wave * 32 + rt * 16 + quad * 4;
        #pragma unroll
        for (int r = 0; r < 4; r++) {
            float inv = 1.0f / l_i[rt][r];
            #pragma unroll
            for (int dt = 0; dt < 4; dt++)
                Og[base + (row + r) * 1024 + dt * 16 + ln] = (__bf16)(o_acc[rt][dt][r] * inv);
        }
    }
}

// ---------------------------------------------------------------------------
extern "C" void kernel_launch(void* const* d_in, const int* in_sizes, int n_in,
                              void* d_out, int out_size, void* d_ws, size_t ws_size,
                              hipStream_t stream)
{
    int* flag = (int*)d_ws;
    __bf16* cv = (__bf16*)((char*)d_ws + 256);

    const int Z = 0, WQ = 8388608, WK = 8454144, WV = 8519680;
    const int FCQW = 8585216, FCKW = 8650752, FCVW = 8716288, FCOW = 8781824;
    const int FCQB = 9830400, FCKB = 9831424, FCVB = 9832448, FCOB = 9833472;
    __bf16* zb = cv + 10485760;
    __bf16* Qw = cv + 12582912;
    __bf16* Kw = Qw + 8388608;
    __bf16* Vw = Kw + 8388608;
    __bf16* Ow = cv + Z;  // reuse z-copy region (dead after proj1)

    detect_dtype<<<1, 256, 0, stream>>>((const unsigned short*)d_in[0], flag);

    ConvArgs ca;
    const int offs[12] = {Z, WQ, WK, WV, FCQW, FCQB, FCKW, FCKB, FCVW, FCVB, FCOW, FCOB};
    for (int i = 0; i < 12; i++) { ca.src[i] = d_in[i]; ca.n[i] = in_sizes[i]; ca.off[i] = offs[i]; }
    convert_inputs<<<dim3(4096, 12), 256, 0, stream>>>(ca, cv, flag);

    gemm_bias<<<dim3(64, 1, 3), 256, 0, stream>>>(
        cv + Z, cv + Z, cv + Z, cv + WQ, cv + WK, cv + WV,
        cv + FCQB, cv + FCQB, cv + FCQB,
        zb, zb + 524288, zb + 1048576, 8192, 64, 1024, 0, nullptr,
        1.0f, 1.0f, 1.0f);

    // Q pre-scaled by 0.125*log2(e) in fp32 epilogue (single bf16 rounding)
    const float QSC = 0.125f * 1.44269504088896f;
    gemm_bias<<<dim3(64, 16, 3), 256, 0, stream>>>(
        zb, zb + 524288, zb + 1048576,
        cv + FCQW, cv + FCKW, cv + FCVW, cv + FCQB, cv + FCKB, cv + FCVB,
        Qw, Kw, Vw, 8192, 1024, 64, 1, nullptr,
        QSC, 1.0f, 1.0f);

    attn_kernel<<<dim3(16, 64), 256, 0, stream>>>(Qw, Kw, Vw, Ow);

    gemm_bias<<<dim3(64, 16, 1), 256, 0, stream>>>(
        Ow, Ow, Ow, cv + FCOW, cv + FCOW, cv + FCOW, cv + FCOB, cv + FCOB, cv + FCOB,
        d_out, d_out, d_out, 8192, 1024, 1024, 1, flag,
        1.0f, 1.0f, 1.0f);
}